// Round 15
// baseline (227.640 us; speedup 1.0000x reference)
//
#include <hip/hip_runtime.h>
#include <hip/hip_bf16.h>
#include <math.h>

#define BB 16
#define LL 4096
#define DD 1024
#define OD 64
#define NP 2016
#define NC 256
#define VD 64
#define NCHUNK 64
#define LCH (LL / NCHUNK)
#define TT 16
#define TPB 256
#define NROW (NP + VD)

typedef __attribute__((ext_vector_type(8))) short bf16x8;
typedef __attribute__((ext_vector_type(4))) float f32x4;

__device__ __forceinline__ int triu_idx(int r, int c) {
  return r * 63 - (r * (r - 1)) / 2 + (c - r - 1);
}
__device__ __forceinline__ unsigned short f2bf(float f) {
  unsigned int u = __float_as_uint(f);
  u += 0x7fffu + ((u >> 16) & 1u);
  return (unsigned short)(u >> 16);
}

// ---------------- Kernel 1a: partial sums (R11 verbatim) ----------------
__global__ void k_partial(const float* __restrict__ x, float* __restrict__ partial) {
  const int b = blockIdx.y, ch = blockIdx.x, tid = threadIdx.x;
  const float4* xp = (const float4*)(x + ((size_t)b * LL + (size_t)ch * LCH) * DD) + tid;
  float4 s = make_float4(0.f, 0.f, 0.f, 0.f);
  #pragma unroll 8
  for (int l = 0; l < LCH; ++l) {
    float4 v = xp[(size_t)l * (DD / 4)];
    s.x += v.x; s.y += v.y; s.z += v.z; s.w += v.w;
  }
  ((float4*)(partial + ((size_t)(b * NCHUNK + ch)) * DD))[tid] = s;
}

// ---------------- Kernel 1b: finalize mean (R14, 256 blocks) ----------
__global__ void k_mean(const float* __restrict__ partial, float* __restrict__ hm) {
  const int ch = blockIdx.x, b = blockIdx.y, tid = threadIdx.x;
  const int col = ch * 64 + (tid & 63), rg = tid >> 6;
  __shared__ float s_red[4][64];
  float s = 0.f;
  const float* pr = partial + (size_t)(b * NCHUNK + rg * 16) * DD + col;
  #pragma unroll
  for (int i = 0; i < 16; ++i) s += pr[(size_t)i * DD];
  s_red[rg][tid & 63] = s;
  __syncthreads();
  if (tid < 64) {
    const float v = s_red[0][tid] + s_red[1][tid] + s_red[2][tid] + s_red[3][tid];
    hm[(size_t)b * DD + ch * 64 + tid] = v * (1.f / (float)LL);
  }
}

// ------- Kernel 2a: 2080-row GEMV (R11 verbatim) ----
__global__ void k_params(const float* __restrict__ hm,
                         const float* __restrict__ opw, const float* __restrict__ opb,
                         const float* __restrict__ viw, const float* __restrict__ vib,
                         float* __restrict__ params, float* __restrict__ vqi_g) {
  const int wave = threadIdx.x >> 6, lane = threadIdx.x & 63;
  const int p = blockIdx.x * 4 + wave;
  if (p >= NROW) return;
  const bool isvq = (p >= NP);
  const float* wr = isvq ? (viw + (size_t)(p - NP) * DD) : (opw + (size_t)p * DD);
  float acc[BB];
  #pragma unroll
  for (int b = 0; b < BB; ++b) acc[b] = 0.f;
  for (int i = 0; i < DD; i += 64) {
    const float wv = wr[i + lane];
    #pragma unroll
    for (int b = 0; b < BB; ++b) acc[b] = fmaf(wv, hm[b * DD + i + lane], acc[b]);
  }
  const float bias = isvq ? vib[p - NP] : opb[p];
  #pragma unroll
  for (int b = 0; b < BB; ++b) {
    float v = acc[b];
    #pragma unroll
    for (int mk = 32; mk; mk >>= 1) v += __shfl_xor(v, mk, 64);
    if (lane == 0) {
      if (isvq) vqi_g[(size_t)b * VD + (p - NP)] = v + bias;
      else      params[(size_t)b * NP + p] = v + bias;
    }
  }
}

// ------- Kernel 2b (fused, WIDE): grid (17,16) x 1024 threads -------------
// chunks 0..15: recompute G in LDS (4 elems/thread, R14 width) then emit the
// MTB e-chunk (G never leaves LDS; saves the k_MTB boundary + G round-trip).
// chunk 16: VQ argmax + cvec. R10's failure was the 256-thread serial version;
// this keeps R14's per-thread work shape exactly.
__global__ __launch_bounds__(1024)
void k_post(const float* __restrict__ params, const float* __restrict__ vqi_g,
            const float* __restrict__ cb,
            const float* __restrict__ oob, const float* __restrict__ vow,
            const float* __restrict__ vob,
            const float* __restrict__ omix_p, const float* __restrict__ vmix_p,
            const float* __restrict__ oow,
            unsigned short* __restrict__ MTB, float* __restrict__ cvec) {
  const int b = blockIdx.y, tid = threadIdx.x;
  const float omix = omix_p[0];
  if (blockIdx.x < 16) {
    __shared__ float om[OD][OD + 1];     // overlaid by wl after gs is built
    __shared__ float om2[OD][OD + 1];
    __shared__ float gs[OD][OD + 1];
    const int eb = blockIdx.x * 64;
    const float* par = params + (size_t)b * NP;
    #pragma unroll
    for (int q = 0; q < 4; ++q) {
      const int e2 = tid + q * 1024;
      const int i = e2 >> 6, j = e2 & 63;
      float v = 0.f;
      if (i < j) v = par[triu_idx(i, j)];
      else if (i > j) v = -par[triu_idx(j, i)];
      om[i][j] = v;
    }
    __syncthreads();
    #pragma unroll
    for (int q = 0; q < 4; ++q) {
      const int e2 = tid + q * 1024;
      const int i = e2 >> 6, j = e2 & 63;
      float s = 0.f;
      #pragma unroll 8
      for (int k = 0; k < OD; ++k) s = fmaf(om[i][k], om[k][j], s);
      om2[i][j] = s;
    }
    __syncthreads();
    #pragma unroll
    for (int q = 0; q < 4; ++q) {
      const int e2 = tid + q * 1024;
      const int i = e2 >> 6, j = e2 & 63;
      float s3 = 0.f;
      #pragma unroll 8
      for (int k = 0; k < OD; ++k) s3 = fmaf(om2[i][k], om[k][j], s3);
      gs[i][j] = om[i][j] + 0.5f * om2[i][j] + (1.f / 6.f) * s3 + (i == j ? 1.f : 0.f);
    }
    __syncthreads();                     // om dead from here -> reuse as wl
    float (*wl)[OD + 1] = om;
    #pragma unroll
    for (int q = 0; q < 4; ++q) {
      const int e2 = tid + q * 1024;
      wl[e2 >> 6][e2 & 63] = oow[(size_t)(eb + (e2 >> 6)) * 64 + (e2 & 63)];
    }
    __syncthreads();
    #pragma unroll
    for (int q = 0; q < 4; ++q) {
      const int o = tid + q * 1024;
      const int el = o >> 6, d = o & 63;
      float s = 0.f;
      #pragma unroll
      for (int k = 0; k < 64; ++k) s = fmaf(gs[d][k], wl[el][k], s);
      MTB[((size_t)b * DD + eb + el) * OD + d] = f2bf(omix * s);
    }
  } else {
    __shared__ float vq[VD];
    __shared__ float scb[NC];
    __shared__ int sib[NC];
    __shared__ float cd[VD];
    __shared__ float nv_s;
    if (tid < VD) vq[tid] = vqi_g[(size_t)b * VD + tid];
    __syncthreads();
    if (tid == 0) {
      float s = 0.f;
      for (int k = 0; k < VD; ++k) s += vq[k] * vq[k];
      nv_s = fmaxf(sqrtf(s), 1e-12f);
    }
    __syncthreads();
    if (tid < NC) {
      const float* cr = cb + (size_t)tid * VD;
      float dot = 0.f, ssq = 0.f;
      #pragma unroll 8
      for (int k = 0; k < VD; ++k) { float cv = cr[k]; dot = fmaf(cv, vq[k], dot); ssq = fmaf(cv, cv, ssq); }
      scb[tid] = dot / (nv_s * fmaxf(sqrtf(ssq), 1e-12f));
      sib[tid] = tid;
    }
    __syncthreads();
    for (int s2 = 128; s2 > 0; s2 >>= 1) {
      if (tid < s2) {
        float a = scb[tid], b2 = scb[tid + s2];
        int ia = sib[tid], ib = sib[tid + s2];
        if (b2 > a || (b2 == a && ib < ia)) { scb[tid] = b2; sib[tid] = ib; }
      }
      __syncthreads();
    }
    const int best = sib[0];
    if (tid < VD) cd[tid] = cb[(size_t)best * VD + tid];
    __syncthreads();
    const float vmix = vmix_p[0];
    {
      const int e = tid;                       // 1024 threads == DD
      float a = vob[e];
      const float* wr = vow + (size_t)e * VD;
      #pragma unroll 8
      for (int k = 0; k < VD; ++k) a = fmaf(cd[k], wr[k], a);
      cvec[(size_t)b * DD + e] = fmaf(omix, oob[e], vmix * a);
    }
  }
}

// ---------------- Kernel 3: MFMA main pass (R11 v6 + nontemporal out) --------
#define STAGE_XH(BUF, TTOK)                                                          \
  if (stager) {                                                                      \
    const float4 v = *(const float4*)(x + xrow + (size_t)((TTOK) + stok) * DD + sd0);\
    unsigned int lo = (unsigned int)f2bf(v.x) | ((unsigned int)f2bf(v.y) << 16);     \
    unsigned int hi = (unsigned int)f2bf(v.z) | ((unsigned int)f2bf(v.w) << 16);     \
    *(uint2*)((char*)&(BUF)[0][0] + stok * 144 + sd0 * 2) = make_uint2(lo, hi);      \
  }

#define LOAD_RES(DST, TTOK)                                                          \
  _Pragma("unroll")                                                                  \
  for (int et = 0; et < 4; ++et) {                                                   \
    _Pragma("unroll")                                                                \
    for (int r = 0; r < 4; ++r)                                                      \
      DST[et][r] = x[xrow + (size_t)((TTOK) + g * 4 + r) * DD + ebase + et * 16 + c];\
  }

#define COMPUTE_TILE(XBUF, RES, PAR, TTOK)                                           \
  {                                                                                  \
    const char* xbB = (const char*)&(XBUF)[0][0];                                    \
    bf16x8 af0 = *(const bf16x8*)(xbB + c * 144 + g * 16);                           \
    bf16x8 af1 = *(const bf16x8*)(xbB + c * 144 + 64 + g * 16);                      \
    f32x4 acc[4];                                                                    \
    _Pragma("unroll")                                                                \
    for (int et = 0; et < 4; ++et) {                                                 \
      acc[et] = (f32x4){0.f, 0.f, 0.f, 0.f};                                         \
      acc[et] = __builtin_amdgcn_mfma_f32_16x16x32_bf16(af0, bf[et][0], acc[et], 0, 0, 0); \
      acc[et] = __builtin_amdgcn_mfma_f32_16x16x32_bf16(af1, bf[et][1], acc[et], 0, 0, 0); \
    }                                                                                \
    float pp[4] = {0.f, 0.f, 0.f, 0.f};                                              \
    _Pragma("unroll")                                                                \
    for (int et = 0; et < 4; ++et) {                                                 \
      _Pragma("unroll")                                                              \
      for (int r = 0; r < 4; ++r) {                                                  \
        const float y = RES[et][r] + acc[et][r] + ce_r[et];                          \
        acc[et][r] = y;                                                              \
        pp[r] = fmaf(y, y, pp[r]);                                                   \
      }                                                                              \
    }                                                                                \
    _Pragma("unroll")                                                                \
    for (int mk = 1; mk < 16; mk <<= 1) {                                            \
      _Pragma("unroll")                                                              \
      for (int r = 0; r < 4; ++r) pp[r] += __shfl_xor(pp[r], mk, 64);                \
    }                                                                                \
    if (c == 0) {                                                                    \
      _Pragma("unroll")                                                              \
      for (int r = 0; r < 4; ++r) red[PAR][g * 4 + r][w] = pp[r];                    \
    }                                                                                \
    __syncthreads();                                                                 \
    float sc_r[4];                                                                   \
    _Pragma("unroll")                                                                \
    for (int r = 0; r < 4; ++r) {                                                    \
      const float4* rp = (const float4*)&red[PAR][g * 4 + r][0];                     \
      const float4 s0 = rp[0], s1 = rp[1], s2 = rp[2], s3 = rp[3];                   \
      const float s = s0.x + s0.y + s0.z + s0.w + s1.x + s1.y + s1.z + s1.w          \
                    + s2.x + s2.y + s2.z + s2.w + s3.x + s3.y + s3.z + s3.w;         \
      sc_r[r] = rsqrtf(s * (1.f / (float)DD) + 1e-6f);                               \
    }                                                                                \
    _Pragma("unroll")                                                                \
    for (int et = 0; et < 4; ++et) {                                                 \
      _Pragma("unroll")                                                              \
      for (int r = 0; r < 4; ++r) {                                                  \
        __builtin_nontemporal_store(acc[et][r] * sc_r[r] * nw_r[et],                 \
            out + xrow + (size_t)((TTOK) + g * 4 + r) * DD + ebase + et * 16 + c);   \
      }                                                                              \
    }                                                                                \
  }

__global__ __launch_bounds__(1024)
void k_mfma(const float* __restrict__ x, const unsigned short* __restrict__ MTB,
            const float* __restrict__ cvec, const float* __restrict__ nw,
            float* __restrict__ out) {
  const int b = blockIdx.y;
  const int Tblk = blockIdx.x * TPB;
  const int tid = threadIdx.x;
  const int w = tid >> 6, lane = tid & 63;
  const int c = lane & 15, g = lane >> 4;
  const int ebase = w * 64;

  __shared__ unsigned short xh[2][TT][72];
  __shared__ float red[2][TT][20];

  bf16x8 bf[4][2];
  {
    const unsigned short* mp = MTB + ((size_t)b * DD + ebase + c) * OD + g * 8;
    #pragma unroll
    for (int et = 0; et < 4; ++et) {
      #pragma unroll
      for (int ks = 0; ks < 2; ++ks)
        bf[et][ks] = *(const bf16x8*)(mp + (size_t)et * 16 * OD + ks * 32);
    }
  }
  float ce_r[4], nw_r[4];
  #pragma unroll
  for (int et = 0; et < 4; ++et) {
    ce_r[et] = cvec[(size_t)b * DD + ebase + et * 16 + c];
    nw_r[et] = nw[ebase + et * 16 + c];
  }

  const size_t xrow = ((size_t)b * LL + Tblk) * DD;
  const int stok = tid >> 4, sd0 = (tid & 15) * 4;
  const bool stager = (tid < 256);

  float resA[4][4], resB[4][4];

  STAGE_XH(xh[0], 0)
  LOAD_RES(resA, 0)
  __syncthreads();

  #pragma unroll 1
  for (int it = 0; it < TPB / (2 * TT); ++it) {
    const int te = it * 2 * TT;
    const int to = te + TT;
    const int tn = te + 2 * TT;
    STAGE_XH(xh[1], to)
    LOAD_RES(resB, to)
    COMPUTE_TILE(xh[0], resA, 0, te)
    if (it + 1 < TPB / (2 * TT)) {
      STAGE_XH(xh[0], tn)
      LOAD_RES(resA, tn)
    }
    COMPUTE_TILE(xh[1], resB, 1, to)
  }
}

extern "C" void kernel_launch(void* const* d_in, const int* in_sizes, int n_in,
                              void* d_out, int out_size, void* d_ws, size_t ws_size,
                              hipStream_t stream) {
  (void)in_sizes; (void)n_in; (void)out_size; (void)ws_size;
  const float* x    = (const float*)d_in[0];
  const float* opw  = (const float*)d_in[1];
  const float* opb  = (const float*)d_in[2];
  const float* oow  = (const float*)d_in[3];
  const float* oob  = (const float*)d_in[4];
  const float* viw  = (const float*)d_in[5];
  const float* vib  = (const float*)d_in[6];
  const float* vow  = (const float*)d_in[7];
  const float* vob  = (const float*)d_in[8];
  const float* cb   = (const float*)d_in[9];
  const float* omix = (const float*)d_in[10];
  const float* vmix = (const float*)d_in[11];
  const float* nw   = (const float*)d_in[12];
  float* out = (float*)d_out;

  float* ws      = (float*)d_ws;
  float* partial = ws;                 // 1048576 floats
  float* hm      = ws + 1048576;       // 16384
  float* params  = ws + 1064960;       // 32256
  float* vqi_g   = ws + 1097216;       // 1024
  unsigned short* MTB = (unsigned short*)(ws + 1098240);  // 1M ushort
  float* cvec    = ws + 1622528;       // 16384

  k_partial<<<dim3(NCHUNK, BB), 256, 0, stream>>>(x, partial);
  k_mean<<<dim3(16, BB), 256, 0, stream>>>(partial, hm);
  k_params<<<NROW / 4, 256, 0, stream>>>(hm, opw, opb, viw, vib, params, vqi_g);
  k_post<<<dim3(17, BB), 1024, 0, stream>>>(params, vqi_g, cb, oob, vow, vob,
                                            omix, vmix, oow, MTB, cvec);
  k_mfma<<<dim3(LL / TPB, BB), 1024, 0, stream>>>(x, MTB, cvec, nw, out);
}

// Round 16
// 210.911 us; speedup vs baseline: 1.0793x; 1.0793x over previous
//
#include <hip/hip_runtime.h>
#include <hip/hip_bf16.h>
#include <math.h>

#define BB 16
#define LL 4096
#define DD 1024
#define OD 64
#define NP 2016
#define NC 256
#define VD 64
#define NCHUNK 64
#define LCH (LL / NCHUNK)
#define TT 16
#define TPB 256
#define NROW (NP + VD)

typedef __attribute__((ext_vector_type(8))) short bf16x8;
typedef __attribute__((ext_vector_type(4))) float f32x4;

__device__ __forceinline__ int triu_idx(int r, int c) {
  return r * 63 - (r * (r - 1)) / 2 + (c - r - 1);
}
__device__ __forceinline__ unsigned short f2bf(float f) {
  unsigned int u = __float_as_uint(f);
  u += 0x7fffu + ((u >> 16) & 1u);
  return (unsigned short)(u >> 16);
}

// ---------------- Kernel 1a: partial sums (R11 verbatim) ----------------
__global__ void k_partial(const float* __restrict__ x, float* __restrict__ partial) {
  const int b = blockIdx.y, ch = blockIdx.x, tid = threadIdx.x;
  const float4* xp = (const float4*)(x + ((size_t)b * LL + (size_t)ch * LCH) * DD) + tid;
  float4 s = make_float4(0.f, 0.f, 0.f, 0.f);
  #pragma unroll 8
  for (int l = 0; l < LCH; ++l) {
    float4 v = xp[(size_t)l * (DD / 4)];
    s.x += v.x; s.y += v.y; s.z += v.z; s.w += v.w;
  }
  ((float4*)(partial + ((size_t)(b * NCHUNK + ch)) * DD))[tid] = s;
}

// ---------------- Kernel 1b: finalize mean (R14, 256 blocks) ----------
__global__ void k_mean(const float* __restrict__ partial, float* __restrict__ hm) {
  const int ch = blockIdx.x, b = blockIdx.y, tid = threadIdx.x;
  const int col = ch * 64 + (tid & 63), rg = tid >> 6;
  __shared__ float s_red[4][64];
  float s = 0.f;
  const float* pr = partial + (size_t)(b * NCHUNK + rg * 16) * DD + col;
  #pragma unroll
  for (int i = 0; i < 16; ++i) s += pr[(size_t)i * DD];
  s_red[rg][tid & 63] = s;
  __syncthreads();
  if (tid < 64) {
    const float v = s_red[0][tid] + s_red[1][tid] + s_red[2][tid] + s_red[3][tid];
    hm[(size_t)b * DD + ch * 64 + tid] = v * (1.f / (float)LL);
  }
}

// ------- Kernel 2a: 2080-row GEMV (R11 verbatim) ----
__global__ void k_params(const float* __restrict__ hm,
                         const float* __restrict__ opw, const float* __restrict__ opb,
                         const float* __restrict__ viw, const float* __restrict__ vib,
                         float* __restrict__ params, float* __restrict__ vqi_g) {
  const int wave = threadIdx.x >> 6, lane = threadIdx.x & 63;
  const int p = blockIdx.x * 4 + wave;
  if (p >= NROW) return;
  const bool isvq = (p >= NP);
  const float* wr = isvq ? (viw + (size_t)(p - NP) * DD) : (opw + (size_t)p * DD);
  float acc[BB];
  #pragma unroll
  for (int b = 0; b < BB; ++b) acc[b] = 0.f;
  for (int i = 0; i < DD; i += 64) {
    const float wv = wr[i + lane];
    #pragma unroll
    for (int b = 0; b < BB; ++b) acc[b] = fmaf(wv, hm[b * DD + i + lane], acc[b]);
  }
  const float bias = isvq ? vib[p - NP] : opb[p];
  #pragma unroll
  for (int b = 0; b < BB; ++b) {
    float v = acc[b];
    #pragma unroll
    for (int mk = 32; mk; mk >>= 1) v += __shfl_xor(v, mk, 64);
    if (lane == 0) {
      if (isvq) vqi_g[(size_t)b * VD + (p - NP)] = v + bias;
      else      params[(size_t)b * NP + p] = v + bias;
    }
  }
}

// ------- Kernel 2b: SPLIT grid (2,16), 1024 threads (R14 verbatim) --------
__global__ __launch_bounds__(1024)
void k_perb(const float* __restrict__ params, const float* __restrict__ vqi_g,
            const float* __restrict__ cb,
            const float* __restrict__ oob, const float* __restrict__ vow,
            const float* __restrict__ vob,
            const float* __restrict__ omix_p, const float* __restrict__ vmix_p,
            float* __restrict__ Gout, float* __restrict__ cvec) {
  const int b = blockIdx.y, tid = threadIdx.x;
  if (blockIdx.x == 0) {
    __shared__ float om[OD][OD + 1];
    __shared__ float om2[OD][OD + 1];
    const float* par = params + (size_t)b * NP;
    #pragma unroll
    for (int q = 0; q < 4; ++q) {
      const int e2 = tid + q * 1024;
      const int i = e2 >> 6, j = e2 & 63;
      float v = 0.f;
      if (i < j) v = par[triu_idx(i, j)];
      else if (i > j) v = -par[triu_idx(j, i)];
      om[i][j] = v;
    }
    __syncthreads();
    #pragma unroll
    for (int q = 0; q < 4; ++q) {
      const int e2 = tid + q * 1024;
      const int i = e2 >> 6, j = e2 & 63;
      float s = 0.f;
      #pragma unroll 8
      for (int k = 0; k < OD; ++k) s = fmaf(om[i][k], om[k][j], s);
      om2[i][j] = s;
    }
    __syncthreads();
    #pragma unroll
    for (int q = 0; q < 4; ++q) {
      const int e2 = tid + q * 1024;
      const int i = e2 >> 6, j = e2 & 63;
      float s3 = 0.f;
      #pragma unroll 8
      for (int k = 0; k < OD; ++k) s3 = fmaf(om2[i][k], om[k][j], s3);
      Gout[(size_t)b * OD * OD + e2] =
          om[i][j] + 0.5f * om2[i][j] + (1.f / 6.f) * s3 + (i == j ? 1.f : 0.f);
    }
  } else {
    __shared__ float vq[VD];
    __shared__ float scb[NC];
    __shared__ int sib[NC];
    __shared__ float cd[VD];
    __shared__ float nv_s;
    if (tid < VD) vq[tid] = vqi_g[(size_t)b * VD + tid];
    __syncthreads();
    if (tid == 0) {
      float s = 0.f;
      for (int k = 0; k < VD; ++k) s += vq[k] * vq[k];
      nv_s = fmaxf(sqrtf(s), 1e-12f);
    }
    __syncthreads();
    if (tid < NC) {
      const float* cr = cb + (size_t)tid * VD;
      float dot = 0.f, ssq = 0.f;
      #pragma unroll 8
      for (int k = 0; k < VD; ++k) { float cv = cr[k]; dot = fmaf(cv, vq[k], dot); ssq = fmaf(cv, cv, ssq); }
      scb[tid] = dot / (nv_s * fmaxf(sqrtf(ssq), 1e-12f));
      sib[tid] = tid;
    }
    __syncthreads();
    for (int s2 = 128; s2 > 0; s2 >>= 1) {
      if (tid < s2) {
        float a = scb[tid], b2 = scb[tid + s2];
        int ia = sib[tid], ib = sib[tid + s2];
        if (b2 > a || (b2 == a && ib < ia)) { scb[tid] = b2; sib[tid] = ib; }
      }
      __syncthreads();
    }
    const int best = sib[0];
    if (tid < VD) cd[tid] = cb[(size_t)best * VD + tid];
    __syncthreads();
    const float omix = omix_p[0], vmix = vmix_p[0];
    {
      const int e = tid;                       // 1024 threads == DD
      float a = vob[e];
      const float* wr = vow + (size_t)e * VD;
      #pragma unroll 8
      for (int k = 0; k < VD; ++k) a = fmaf(cd[k], wr[k], a);
      cvec[(size_t)b * DD + e] = fmaf(omix, oob[e], vmix * a);
    }
  }
}

// ------- Kernel 2c: MTB (R14 verbatim: 1024 threads, 4 outputs/thread) -----
__global__ __launch_bounds__(1024)
void k_MTB(const float* __restrict__ G, const float* __restrict__ oow,
           const float* __restrict__ omix_p, unsigned short* __restrict__ MTB) {
  const int b = blockIdx.y, eb = blockIdx.x * 64, tid = threadIdx.x;
  __shared__ float g[OD][OD + 1];
  __shared__ float wl[64][65];
  #pragma unroll
  for (int q = 0; q < 4; ++q) {
    const int e2 = tid + q * 1024;
    g[e2 >> 6][e2 & 63] = G[(size_t)b * OD * OD + e2];
    wl[e2 >> 6][e2 & 63] = oow[(size_t)(eb + (e2 >> 6)) * 64 + (e2 & 63)];
  }
  __syncthreads();
  const float omix = omix_p[0];
  #pragma unroll
  for (int q = 0; q < 4; ++q) {
    const int o = tid + q * 1024;
    const int el = o >> 6, d = o & 63;
    float s = 0.f;
    #pragma unroll
    for (int k = 0; k < 64; ++k) s = fmaf(g[d][k], wl[el][k], s);
    MTB[((size_t)b * DD + eb + el) * OD + d] = f2bf(omix * s);
  }
}

// ---------------- Kernel 3: MFMA main pass (R11 v6, verbatim; regular stores)
#define STAGE_XH(BUF, TTOK)                                                          \
  if (stager) {                                                                      \
    const float4 v = *(const float4*)(x + xrow + (size_t)((TTOK) + stok) * DD + sd0);\
    unsigned int lo = (unsigned int)f2bf(v.x) | ((unsigned int)f2bf(v.y) << 16);     \
    unsigned int hi = (unsigned int)f2bf(v.z) | ((unsigned int)f2bf(v.w) << 16);     \
    *(uint2*)((char*)&(BUF)[0][0] + stok * 144 + sd0 * 2) = make_uint2(lo, hi);      \
  }

#define LOAD_RES(DST, TTOK)                                                          \
  _Pragma("unroll")                                                                  \
  for (int et = 0; et < 4; ++et) {                                                   \
    _Pragma("unroll")                                                                \
    for (int r = 0; r < 4; ++r)                                                      \
      DST[et][r] = x[xrow + (size_t)((TTOK) + g * 4 + r) * DD + ebase + et * 16 + c];\
  }

#define COMPUTE_TILE(XBUF, RES, PAR, TTOK)                                           \
  {                                                                                  \
    const char* xbB = (const char*)&(XBUF)[0][0];                                    \
    bf16x8 af0 = *(const bf16x8*)(xbB + c * 144 + g * 16);                           \
    bf16x8 af1 = *(const bf16x8*)(xbB + c * 144 + 64 + g * 16);                      \
    f32x4 acc[4];                                                                    \
    _Pragma("unroll")                                                                \
    for (int et = 0; et < 4; ++et) {                                                 \
      acc[et] = (f32x4){0.f, 0.f, 0.f, 0.f};                                         \
      acc[et] = __builtin_amdgcn_mfma_f32_16x16x32_bf16(af0, bf[et][0], acc[et], 0, 0, 0); \
      acc[et] = __builtin_amdgcn_mfma_f32_16x16x32_bf16(af1, bf[et][1], acc[et], 0, 0, 0); \
    }                                                                                \
    float pp[4] = {0.f, 0.f, 0.f, 0.f};                                              \
    _Pragma("unroll")                                                                \
    for (int et = 0; et < 4; ++et) {                                                 \
      _Pragma("unroll")                                                              \
      for (int r = 0; r < 4; ++r) {                                                  \
        const float y = RES[et][r] + acc[et][r] + ce_r[et];                          \
        acc[et][r] = y;                                                              \
        pp[r] = fmaf(y, y, pp[r]);                                                   \
      }                                                                              \
    }                                                                                \
    _Pragma("unroll")                                                                \
    for (int mk = 1; mk < 16; mk <<= 1) {                                            \
      _Pragma("unroll")                                                              \
      for (int r = 0; r < 4; ++r) pp[r] += __shfl_xor(pp[r], mk, 64);                \
    }                                                                                \
    if (c == 0) {                                                                    \
      _Pragma("unroll")                                                              \
      for (int r = 0; r < 4; ++r) red[PAR][g * 4 + r][w] = pp[r];                    \
    }                                                                                \
    __syncthreads();                                                                 \
    float sc_r[4];                                                                   \
    _Pragma("unroll")                                                                \
    for (int r = 0; r < 4; ++r) {                                                    \
      const float4* rp = (const float4*)&red[PAR][g * 4 + r][0];                     \
      const float4 s0 = rp[0], s1 = rp[1], s2 = rp[2], s3 = rp[3];                   \
      const float s = s0.x + s0.y + s0.z + s0.w + s1.x + s1.y + s1.z + s1.w          \
                    + s2.x + s2.y + s2.z + s2.w + s3.x + s3.y + s3.z + s3.w;         \
      sc_r[r] = rsqrtf(s * (1.f / (float)DD) + 1e-6f);                               \
    }                                                                                \
    _Pragma("unroll")                                                                \
    for (int et = 0; et < 4; ++et) {                                                 \
      _Pragma("unroll")                                                              \
      for (int r = 0; r < 4; ++r) {                                                  \
        out[xrow + (size_t)((TTOK) + g * 4 + r) * DD + ebase + et * 16 + c] =        \
            acc[et][r] * sc_r[r] * nw_r[et];                                         \
      }                                                                              \
    }                                                                                \
  }

__global__ __launch_bounds__(1024)
void k_mfma(const float* __restrict__ x, const unsigned short* __restrict__ MTB,
            const float* __restrict__ cvec, const float* __restrict__ nw,
            float* __restrict__ out) {
  const int b = blockIdx.y;
  const int Tblk = blockIdx.x * TPB;
  const int tid = threadIdx.x;
  const int w = tid >> 6, lane = tid & 63;
  const int c = lane & 15, g = lane >> 4;
  const int ebase = w * 64;

  __shared__ unsigned short xh[2][TT][72];
  __shared__ float red[2][TT][20];

  bf16x8 bf[4][2];
  {
    const unsigned short* mp = MTB + ((size_t)b * DD + ebase + c) * OD + g * 8;
    #pragma unroll
    for (int et = 0; et < 4; ++et) {
      #pragma unroll
      for (int ks = 0; ks < 2; ++ks)
        bf[et][ks] = *(const bf16x8*)(mp + (size_t)et * 16 * OD + ks * 32);
    }
  }
  float ce_r[4], nw_r[4];
  #pragma unroll
  for (int et = 0; et < 4; ++et) {
    ce_r[et] = cvec[(size_t)b * DD + ebase + et * 16 + c];
    nw_r[et] = nw[ebase + et * 16 + c];
  }

  const size_t xrow = ((size_t)b * LL + Tblk) * DD;
  const int stok = tid >> 4, sd0 = (tid & 15) * 4;
  const bool stager = (tid < 256);

  float resA[4][4], resB[4][4];

  STAGE_XH(xh[0], 0)
  LOAD_RES(resA, 0)
  __syncthreads();

  #pragma unroll 1
  for (int it = 0; it < TPB / (2 * TT); ++it) {
    const int te = it * 2 * TT;
    const int to = te + TT;
    const int tn = te + 2 * TT;
    STAGE_XH(xh[1], to)
    LOAD_RES(resB, to)
    COMPUTE_TILE(xh[0], resA, 0, te)
    if (it + 1 < TPB / (2 * TT)) {
      STAGE_XH(xh[0], tn)
      LOAD_RES(resA, tn)
    }
    COMPUTE_TILE(xh[1], resB, 1, to)
  }
}

extern "C" void kernel_launch(void* const* d_in, const int* in_sizes, int n_in,
                              void* d_out, int out_size, void* d_ws, size_t ws_size,
                              hipStream_t stream) {
  (void)in_sizes; (void)n_in; (void)out_size; (void)ws_size;
  const float* x    = (const float*)d_in[0];
  const float* opw  = (const float*)d_in[1];
  const float* opb  = (const float*)d_in[2];
  const float* oow  = (const float*)d_in[3];
  const float* oob  = (const float*)d_in[4];
  const float* viw  = (const float*)d_in[5];
  const float* vib  = (const float*)d_in[6];
  const float* vow  = (const float*)d_in[7];
  const float* vob  = (const float*)d_in[8];
  const float* cb   = (const float*)d_in[9];
  const float* omix = (const float*)d_in[10];
  const float* vmix = (const float*)d_in[11];
  const float* nw   = (const float*)d_in[12];
  float* out = (float*)d_out;

  float* ws      = (float*)d_ws;
  float* partial = ws;                 // 1048576 floats
  float* hm      = ws + 1048576;       // 16384
  float* params  = ws + 1064960;       // 32256
  float* vqi_g   = ws + 1097216;       // 1024
  float* G       = ws + 1098240;       // 65536
  unsigned short* MTB = (unsigned short*)(ws + 1163776);  // 1M ushort
  float* cvec    = ws + 1688064;       // 16384

  k_partial<<<dim3(NCHUNK, BB), 256, 0, stream>>>(x, partial);
  k_mean<<<dim3(16, BB), 256, 0, stream>>>(partial, hm);
  k_params<<<NROW / 4, 256, 0, stream>>>(hm, opw, opb, viw, vib, params, vqi_g);
  k_perb<<<dim3(2, BB), 1024, 0, stream>>>(params, vqi_g, cb, oob, vow, vob,
                                           omix, vmix, G, cvec);
  k_MTB<<<dim3(16, BB), 1024, 0, stream>>>(G, oow, omix, MTB);
  k_mfma<<<dim3(LL / TPB, BB), 1024, 0, stream>>>(x, MTB, cvec, nw, out);
}